// Round 19
// baseline (225.055 us; speedup 1.0000x reference)
//
#include <hip/hip_runtime.h>
#include <hip/hip_bf16.h>

typedef __bf16 bf16;
typedef __bf16 bf16x4 __attribute__((ext_vector_type(4)));
typedef __bf16 bf16x8 __attribute__((ext_vector_type(8)));
typedef float  f32x4  __attribute__((ext_vector_type(4)));

#define NN 4096
#define KK 16
#define CC 128
#define BN_TOT 16384

// ---------------------------------------------------------------------------
// K1/K5: Y = A(f32) @ W^T(f32) + b (fp32 out) + bn partials.  MFMA 16x16x32.
// SPLIT by output-column half: 512 blocks (row-group x col-half), 256 thr.
// 34 KB LDS -> 2 blocks/CU; each block stages 32 KB of W.
// partial[blk*128 + 0..63]=sum, [64..127]=sumsq for channels ch*64+j.
// ---------------------------------------------------------------------------
__global__ __launch_bounds__(256) void k_lin(
    const float* __restrict__ A, const float* __restrict__ W,
    const float* __restrict__ bias, float* __restrict__ Y,
    float* __restrict__ partial) {
  __shared__ __attribute__((aligned(16))) bf16 WF[16 * 64 * 8];   // 16384 B
  __shared__ __attribute__((aligned(16))) float SF[4][16][68];    // 17408 B
  __shared__ float P1[64], P2[64];
  int tid = threadIdx.x, w = tid >> 6, l = tid & 63, quad = l >> 4, col = l & 15;
  int rb = blockIdx.x >> 1, ch = blockIdx.x & 1;
  int r0 = rb * 64, cbase = ch * 64;
  int arow = r0 + w * 16 + col;

  if (tid < 64) { P1[tid] = 0.f; P2[tid] = 0.f; }

  // stage W rows cbase..cbase+63 (64x128 f32 -> bf16), fragment-linear
  for (int e = tid; e < 64 * 16; e += 256) {
    int r = e >> 4, c8 = e & 15;
    const float* p = W + (cbase + r) * CC + c8 * 8;
    f32x4 v0 = *(const f32x4*)p, v1 = *(const f32x4*)(p + 4);
    bf16x8 o;
    for (int i = 0; i < 4; i++) { o[i] = (bf16)v0[i]; o[i + 4] = (bf16)v1[i]; }
    int chunk = (r >> 4) * 4 + (c8 >> 2);
    int lane  = (c8 & 3) * 16 + (r & 15);
    *(bf16x8*)(&WF[(chunk * 64 + lane) * 8]) = o;
  }

  // A-frags direct from global (full K=128)
  bf16x8 a[4];
  for (int kc = 0; kc < 4; kc++) {
    int c0 = kc * 32 + quad * 8;
    f32x4 y0 = *(const f32x4*)(A + arow * CC + c0);
    f32x4 y1 = *(const f32x4*)(A + arow * CC + c0 + 4);
    bf16x8 o;
    for (int i = 0; i < 4; i++) { o[i] = (bf16)y0[i]; o[i + 4] = (bf16)y1[i]; }
    a[kc] = o;
  }

  f32x4 D[4];
  for (int jb = 0; jb < 4; jb++) {
    float bv = bias[cbase + jb * 16 + col];
    D[jb] = (f32x4){bv, bv, bv, bv};
  }
  __syncthreads();
  for (int jb = 0; jb < 4; jb++)
    for (int kc = 0; kc < 4; kc++) {
      bf16x8 bfrag = *(const bf16x8*)(&WF[((jb * 4 + kc) * 64 + l) * 8]);
      D[jb] = __builtin_amdgcn_mfma_f32_16x16x32_bf16(a[kc], bfrag, D[jb], 0, 0, 0);
    }

  // bn partials (this block's 64 rows x 64 channels)
  for (int jb = 0; jb < 4; jb++) {
    float t1 = D[jb][0] + D[jb][1] + D[jb][2] + D[jb][3];
    float t2 = D[jb][0] * D[jb][0] + D[jb][1] * D[jb][1]
             + D[jb][2] * D[jb][2] + D[jb][3] * D[jb][3];
    t1 += __shfl_xor(t1, 16); t1 += __shfl_xor(t1, 32);
    t2 += __shfl_xor(t2, 16); t2 += __shfl_xor(t2, 32);
    if (quad == 0) {
      atomicAdd(&P1[jb * 16 + col], t1);
      atomicAdd(&P2[jb * 16 + col], t2);
    }
  }

  // fp32 store via per-wave f32 scratch (wave-local: no barrier needed)
  for (int jb = 0; jb < 4; jb++)
    for (int g = 0; g < 4; g++)
      SF[w][quad * 4 + g][jb * 16 + col] = D[jb][g];
  int orow = r0 + w * 16 + (l >> 2), oc = (l & 3) * 16;
  for (int c4 = 0; c4 < 4; c4++) {
    f32x4 v = *(const f32x4*)(&SF[w][l >> 2][oc + c4 * 4]);
    *(f32x4*)(Y + orow * CC + cbase + oc + c4 * 4) = v;
  }

  __syncthreads();  // all waves' LDS atomics done
  if (tid < 64) {
    partial[blockIdx.x * 128 + tid] = P1[tid];
    partial[blockIdx.x * 128 + 64 + tid] = P2[tid];
  }
}

// ---------------------------------------------------------------------------
// PARALLEL finalize: 8 blocks x 256 thr.  Block b owns channels b*16..b*16+15;
// thread (t&15)=channel offset, (t>>4)=group g sums rb = g, g+16, ..., g+240.
// ---------------------------------------------------------------------------
__global__ __launch_bounds__(256) void k_finalize(
    const float* __restrict__ partial, const float* __restrict__ g,
    const float* __restrict__ b, float* __restrict__ stats) {
  __shared__ float sh[2][16][16];
  int t = threadIdx.x, cl = t & 15, gr = t >> 4;   // 16 groups of 16 channels
  int c = blockIdx.x * 16 + cl;
  int ch = c >> 6, j = c & 63;
  float s1 = 0.f, s2 = 0.f;
  for (int rb = gr; rb < 256; rb += 16) {
    const float* pp = partial + (rb * 2 + ch) * 128;
    s1 += pp[j];
    s2 += pp[64 + j];
  }
  sh[0][gr][cl] = s1; sh[1][gr][cl] = s2;
  __syncthreads();
  if (t < 16) {
    s1 = 0.f; s2 = 0.f;
    for (int hh = 0; hh < 16; hh++) {
      s1 += sh[0][hh][t];
      s2 += sh[1][hh][t];
    }
    int cc = blockIdx.x * 16 + t;
    float mean = s1 * (1.0f / BN_TOT);
    float var  = s2 * (1.0f / BN_TOT) - mean * mean;
    float r = rsqrtf(var + 1e-5f);
    float sc = g[cc] * r;
    stats[cc] = sc;
    stats[128 + cc] = b[cc] - mean * sc;
  }
}

// ---------------------------------------------------------------------------
// K3: x = relu(bn2(y2)); q/k/v = x @ W^T (bf16 out).  NO LDS WEIGHT STAGING:
// 16 B-frags held in REGISTERS, loaded directly from global (L2-hot — all
// blocks share 3x64KB) and issued FIRST so the A-frag loads + bn math cover
// their latency.  1536 blocks (3m x 2ch x 256rb), LDS only 8.7KB (S) ->
// many blocks/CU for TLP.  No __syncthreads at all (S is per-wave).
// __launch_bounds__(256,1): proven-faithful allocator config (r7: 212 VGPR).
// ---------------------------------------------------------------------------
__global__ __launch_bounds__(256, 1) void k_qkv(
    const float* __restrict__ Y, const float* __restrict__ stats,
    const float* __restrict__ Wq, const float* __restrict__ Wk, const float* __restrict__ Wv,
    bf16* __restrict__ Qo, bf16* __restrict__ Ko, bf16* __restrict__ Vo) {
  __shared__ __attribute__((aligned(16))) bf16 S[4][16][68];      // 8704 B
  int tid = threadIdx.x, w = tid >> 6, l = tid & 63, quad = l >> 4, col = l & 15;
  int x8 = blockIdx.x & 7, lj = blockIdx.x >> 3;   // lj in [0,192)
  int rb = x8 * 32 + (lj & 31);
  int mch = lj >> 5;                                // 0..5
  int m = mch >> 1, ch = mch & 1;
  int r0 = rb * 64, cbase = ch * 64;
  int arow = r0 + w * 16 + col;
  const float* Wg = (m == 0) ? Wq : (m == 1) ? Wk : Wv;
  bf16* Os = (m == 0) ? Qo : (m == 1) ? Ko : Vo;

  // B-frags direct from global, issued first.  Frag (jb,kc): lane l reads
  // W[cbase + jb*16 + col][kc*32 + quad*8 .. +8)  (row-major f32 -> bf16x8)
  bf16x8 bW[16];
#pragma unroll
  for (int jb = 0; jb < 4; jb++)
#pragma unroll
    for (int kc = 0; kc < 4; kc++) {
      const float* p = Wg + (cbase + jb * 16 + col) * CC + kc * 32 + quad * 8;
      f32x4 v0 = *(const f32x4*)p, v1 = *(const f32x4*)(p + 4);
      bf16x8 o;
#pragma unroll
      for (int i = 0; i < 4; i++) { o[i] = (bf16)v0[i]; o[i + 4] = (bf16)v1[i]; }
      bW[jb * 4 + kc] = o;
    }

  // A-frags: x = relu(bn(Y)) -> bf16 (overlaps outstanding W loads)
  bf16x8 a[4];
#pragma unroll
  for (int kc = 0; kc < 4; kc++) {
    int c0 = kc * 32 + quad * 8;
    f32x4 y0  = *(const f32x4*)(Y + arow * CC + c0);
    f32x4 y1  = *(const f32x4*)(Y + arow * CC + c0 + 4);
    f32x4 sc0 = *(const f32x4*)(stats + c0);
    f32x4 sc1 = *(const f32x4*)(stats + c0 + 4);
    f32x4 sf0 = *(const f32x4*)(stats + 128 + c0);
    f32x4 sf1 = *(const f32x4*)(stats + 128 + c0 + 4);
    bf16x8 o;
#pragma unroll
    for (int i = 0; i < 4; i++) {
      o[i]     = (bf16)fmaxf(y0[i] * sc0[i] + sf0[i], 0.f);
      o[i + 4] = (bf16)fmaxf(y1[i] * sc1[i] + sf1[i], 0.f);
    }
    a[kc] = o;
  }

  f32x4 D[4];
#pragma unroll
  for (int jb = 0; jb < 4; jb++) D[jb] = (f32x4){0.f, 0.f, 0.f, 0.f};
#pragma unroll
  for (int jb = 0; jb < 4; jb++)
#pragma unroll
    for (int kc = 0; kc < 4; kc++)
      D[jb] = __builtin_amdgcn_mfma_f32_16x16x32_bf16(a[kc], bW[jb * 4 + kc], D[jb], 0, 0, 0);

  // bf16 out via per-wave S roundtrip (same-wave in-order; no barrier)
#pragma unroll
  for (int jb = 0; jb < 4; jb++)
#pragma unroll
    for (int g = 0; g < 4; g++)
      S[w][quad * 4 + g][jb * 16 + col] = (bf16)D[jb][g];
  int orow = r0 + w * 16 + (l >> 2), oc = (l & 3) * 16;
#pragma unroll
  for (int c8 = 0; c8 < 2; c8++) {
    bf16x8 v = *(const bf16x8*)(&S[w][l >> 2][oc + c8 * 8]);
    *(bf16x8*)(Os + orow * CC + cbase + oc + c8 * 8) = v;
  }
}

// ---------------------------------------------------------------------------
// K4: MFMA attention core — best measured (r13/r14/r16/r18: ~68us, VGPR 112).
// 512 thr = 8 waves; 64 points/block (8/wave); grid 256 (XCD-chunked).
// All weights LDS-resident; h1 via padded MFMA; no-max softmax; V-gather +
// K-row loads hoisted under MFMA phases; knn/pose double-buffered.
// A-frag: lane holds X[m=l&15][k=quad*8+j].  D: row=quad*4+g, col=jb*16+(l&15).
// ---------------------------------------------------------------------------
__global__ __launch_bounds__(512) void k_attn(
    const bf16* __restrict__ Q, const bf16* __restrict__ Kf, const bf16* __restrict__ Vf,
    const int* __restrict__ knn, const float* __restrict__ pose,
    const float* __restrict__ d_w1, const float* __restrict__ d_b1,
    const float* __restrict__ d_w2, const float* __restrict__ d_b2,
    const float* __restrict__ g_w1, const float* __restrict__ g_b1,
    const float* __restrict__ g_w2, const float* __restrict__ g_b2,
    float* __restrict__ Rs) {
  __shared__ __attribute__((aligned(16))) bf16 WF[104 * 64 * 8];  // 106496 B
  __shared__ __attribute__((aligned(16))) bf16 S[8][16][132];     // 33792 B
  __shared__ float BSf[512];                                      // 2048 B

  int tid = threadIdx.x, w = tid >> 6, l = tid & 63, quad = l >> 4, col = l & 15;
  int bid = (blockIdx.x & 7) * 32 + (blockIdx.x >> 3);  // XCD-chunked swizzle

  // stage the three 128x128 weights, fragment-linear (chunks 0..95)
  const float* Wg3[3] = {d_w2, g_w1, g_w2};
  for (int m = 0; m < 3; m++) {
    const float* Wg = Wg3[m];
    for (int e = tid; e < 128 * 16; e += 512) {
      int r = e >> 4, c8 = e & 15;
      const float* p = Wg + r * CC + c8 * 8;
      f32x4 v0 = *(const f32x4*)p, v1 = *(const f32x4*)(p + 4);
      bf16x8 o;
      for (int i = 0; i < 4; i++) { o[i] = (bf16)v0[i]; o[i + 4] = (bf16)v1[i]; }
      int chunk = m * 32 + (r >> 4) * 4 + (c8 >> 2);
      int lane  = (c8 & 3) * 16 + (r & 15);
      *(bf16x8*)(&WF[(chunk * 64 + lane) * 8]) = o;
    }
  }
  // d_w1 as K=4-in-32 padded B-frags (chunks 96..103): nonzero only quad 0, j<4
  for (int e = tid; e < 8 * 64; e += 512) {
    int jb = e >> 6, lane = e & 63, q = lane >> 4, c = lane & 15;
    bf16x8 o;
    for (int i = 0; i < 8; i++) o[i] = (bf16)0.f;
    if (q == 0) {
      f32x4 v = *(const f32x4*)(d_w1 + (jb * 16 + c) * 4);
      for (int i = 0; i < 4; i++) o[i] = (bf16)v[i];
    }
    *(bf16x8*)(&WF[((96 + jb) * 64 + lane) * 8]) = o;
  }
  // biases: d_b1 | d_b2 | g_b1 | g_b2
  if (tid < 512) {
    const float* bp = (tid < 128) ? d_b1 : (tid < 256) ? d_b2
                     : (tid < 384) ? g_b1 : g_b2;
    BSf[tid] = bp[tid & 127];
  }
  __syncthreads();

  const float smc = 0.08838834764831845f;  // 1/sqrt(128)

  // preload point 0's knn/pose
  int gpf = bid * 64 + w * 8;
  int i16 = knn[gpf * KK + col];
  f32x4 ps = *(const f32x4*)(pose + gpf * 64 + col * 4);

#pragma unroll 1
  for (int p = 0; p < 8; p++) {
    int gp = bid * 64 + w * 8 + p;
    int b  = gp >> 12;

    // --- EARLY V gather (consumed at vpos; covered by h1+pos MFMAs) ---
    int vidx[4];
#pragma unroll
    for (int g = 0; g < 4; g++) vidx[g] = __shfl(i16, quad * 4 + g);
    float vv[8][4];
#pragma unroll
    for (int g = 0; g < 4; g++) {
      const bf16* vr = Vf + ((b << 12) + vidx[g]) * CC + col;
#pragma unroll
      for (int jb = 0; jb < 8; jb++) vv[jb][g] = (float)vr[jb * 16];
    }
    int grow = (b << 12) + i16;

    // --- h1 = relu(pose @ d_w1^T + d_b1) via padded MFMA (K=4 in 32) ---
    bf16x8 ap;
#pragma unroll
    for (int j = 0; j < 8; j++) ap[j] = (bf16)0.f;
    if (quad == 0) {
#pragma unroll
      for (int j = 0; j < 4; j++) ap[j] = (bf16)ps[j];
    }
    f32x4 D[8];
#pragma unroll
    for (int jb = 0; jb < 8; jb++) {
      float bv = BSf[jb * 16 + col];
      D[jb] = (f32x4){bv, bv, bv, bv};
      bf16x8 bfrag = *(const bf16x8*)(&WF[((96 + jb) * 64 + l) * 8]);
      D[jb] = __builtin_amdgcn_mfma_f32_16x16x32_bf16(ap, bfrag, D[jb], 0, 0, 0);
    }
#pragma unroll
    for (int jb = 0; jb < 8; jb++)
#pragma unroll
      for (int g = 0; g < 4; g++)
        S[w][quad * 4 + g][jb * 16 + col] = (bf16)fmaxf(D[jb][g], 0.f);
    bf16x8 aA[4];
#pragma unroll
    for (int kc = 0; kc < 4; kc++)
      aA[kc] = *(const bf16x8*)(&S[w][col][kc * 32 + quad * 8]);

    // --- EARLY K-row loads (consumed in h-phase; covered by pos MFMAs) ---
    bf16x8 kkv[4];
#pragma unroll
    for (int kc = 0; kc < 4; kc++)
      kkv[kc] = *(const bf16x8*)(Kf + grow * CC + kc * 32 + quad * 8);

    // --- prefetch next point's knn/pose ---
    if (p < 7) {
      i16 = knn[(gp + 1) * KK + col];
      ps  = *(const f32x4*)(pose + (gp + 1) * 64 + col * 4);
    }

    // --- pos = h1 @ d_w2^T + d_b2  (B-frags from LDS chunks 0..31) ---
#pragma unroll
    for (int jb = 0; jb < 8; jb++) {
      float bv = BSf[128 + jb * 16 + col];
      D[jb] = (f32x4){bv, bv, bv, bv};
    }
#pragma unroll
    for (int jb = 0; jb < 8; jb++)
#pragma unroll
      for (int kc = 0; kc < 4; kc++) {
        bf16x8 bfrag = *(const bf16x8*)(&WF[((jb * 4 + kc) * 64 + l) * 8]);
        D[jb] = __builtin_amdgcn_mfma_f32_16x16x32_bf16(aA[kc], bfrag, D[jb], 0, 0, 0);
      }

    // --- vpos = vv + pos (in place) ---
#pragma unroll
    for (int jb = 0; jb < 8; jb++)
#pragma unroll
      for (int g = 0; g < 4; g++) vv[jb][g] += D[jb][g];

    // --- pos -> S; h = q - kk + pos in A layout ---
#pragma unroll
    for (int jb = 0; jb < 8; jb++)
#pragma unroll
      for (int g = 0; g < 4; g++)
        S[w][quad * 4 + g][jb * 16 + col] = (bf16)D[jb][g];
#pragma unroll
    for (int kc = 0; kc < 4; kc++) {
      int c0 = kc * 32 + quad * 8;
      bf16x8 qv = *(const bf16x8*)(Q + gp * CC + c0);
      bf16x8 pv = *(const bf16x8*)(&S[w][col][c0]);
      bf16x8 hv;
#pragma unroll
      for (int j = 0; j < 8; j++)
        hv[j] = (bf16)((float)qv[j] - (float)kkv[kc][j] + (float)pv[j]);
      aA[kc] = hv;
    }

    // --- t = relu(h @ g_w1^T + g_b1)  (chunks 32..63) ---
#pragma unroll
    for (int jb = 0; jb < 8; jb++) {
      float bv = BSf[256 + jb * 16 + col];
      D[jb] = (f32x4){bv, bv, bv, bv};
    }
#pragma unroll
    for (int jb = 0; jb < 8; jb++)
#pragma unroll
      for (int kc = 0; kc < 4; kc++) {
        bf16x8 bfrag = *(const bf16x8*)(&WF[((32 + jb * 4 + kc) * 64 + l) * 8]);
        D[jb] = __builtin_amdgcn_mfma_f32_16x16x32_bf16(aA[kc], bfrag, D[jb], 0, 0, 0);
      }
#pragma unroll
    for (int jb = 0; jb < 8; jb++)
#pragma unroll
      for (int g = 0; g < 4; g++)
        S[w][quad * 4 + g][jb * 16 + col] = (bf16)fmaxf(D[jb][g], 0.f);
#pragma unroll
    for (int kc = 0; kc < 4; kc++)
      aA[kc] = *(const bf16x8*)(&S[w][col][kc * 32 + quad * 8]);

    // --- logits = t @ g_w2^T + g_b2  (chunks 64..95) ---
#pragma unroll
    for (int jb = 0; jb < 8; jb++) {
      float bv = BSf[384 + jb * 16 + col];
      D[jb] = (f32x4){bv, bv, bv, bv};
    }
#pragma unroll
    for (int jb = 0; jb < 8; jb++)
#pragma unroll
      for (int kc = 0; kc < 4; kc++) {
        bf16x8 bfrag = *(const bf16x8*)(&WF[((64 + jb * 4 + kc) * 64 + l) * 8]);
        D[jb] = __builtin_amdgcn_mfma_f32_16x16x32_bf16(aA[kc], bfrag, D[jb], 0, 0, 0);
      }

    // --- softmax over k (no max-sub: logits bounded ~O(1); proven r5-r18) ---
#pragma unroll
    for (int jb = 0; jb < 8; jb++) {
      float s = 0.f, pa = 0.f;
#pragma unroll
      for (int g = 0; g < 4; g++) {
        float e = __expf(D[jb][g] * smc);
        s += e; pa += e * vv[jb][g];
      }
      s  += __shfl_xor(s, 16);  s += __shfl_xor(s, 32);
      pa += __shfl_xor(pa, 16); pa += __shfl_xor(pa, 32);
      if (quad == 0) Rs[gp * CC + jb * 16 + col] = pa / s;
    }
  }
}

// ---------------------------------------------------------------------------
// K7: out = relu(bn1(y1)) + new_points   (fp32 out)
// ---------------------------------------------------------------------------
__global__ __launch_bounds__(256) void k_out(
    const float* __restrict__ Y, const float* __restrict__ stats,
    const float* __restrict__ NP, float* __restrict__ Out) {
  int i0 = (blockIdx.x * 256 + threadIdx.x) * 4;
  int c0 = i0 & 127;
  f32x4 y  = *(const f32x4*)(Y + i0);
  f32x4 sc = *(const f32x4*)(stats + c0);
  f32x4 sh = *(const f32x4*)(stats + 128 + c0);
  f32x4 np = *(const f32x4*)(NP + i0);
  f32x4 o;
  for (int i = 0; i < 4; i++)
    o[i] = fmaxf(y[i] * sc[i] + sh[i], 0.f) + np[i];
  *(f32x4*)(Out + i0) = o;
}

__global__ void k_code(float* out, float code) {
  if (threadIdx.x == 0) out[1000003] = code;
}

// ---------------------------------------------------------------------------
extern "C" void kernel_launch(void* const* d_in, const int* in_sizes, int n_in,
                              void* d_out, int out_size, void* d_ws, size_t ws_size,
                              hipStream_t stream) {
  static const int expect[22] = {
    1048576, 262144, 2097152, 16384, 16384, 16384,
    16384, 128, 16384, 128,
    512, 128, 16384, 128,
    16384, 128, 128, 128,
    16384, 128, 128, 128
  };
  if (n_in != 22) { k_code<<<1, 64, 0, stream>>>((float*)d_out, 4194304.f); return; }
  for (int i = 0; i < 22; i++)
    if (in_sizes[i] != expect[i]) {
      k_code<<<1, 64, 0, stream>>>((float*)d_out, 262144.f * (float)(i + 1));
      return;
    }

  const float* pose  = (const float*)d_in[0];
  const int*   knn   = (const int*)d_in[1];
  const float* np_   = (const float*)d_in[2];
  const float* wq    = (const float*)d_in[3];
  const float* wk    = (const float*)d_in[4];
  const float* wv    = (const float*)d_in[5];
  const float* g_w1  = (const float*)d_in[6];
  const float* g_b1  = (const float*)d_in[7];
  const float* g_w2  = (const float*)d_in[8];
  const float* g_b2  = (const float*)d_in[9];
  const float* d_w1  = (const float*)d_in[10];
  const float* d_b1  = (const float*)d_in[11];
  const float* d_w2  = (const float*)d_in[12];
  const float* d_b2  = (const float*)d_in[13];
  const float* c1_w  = (const float*)d_in[14];
  const float* c1_b  = (const float*)d_in[15];
  const float* bn1_g = (const float*)d_in[16];
  const float* bn1_b = (const float*)d_in[17];
  const float* c2_w  = (const float*)d_in[18];
  const float* c2_b  = (const float*)d_in[19];
  const float* bn2_g = (const float*)d_in[20];
  const float* bn2_b = (const float*)d_in[21];

  float* y2      = (float*)d_ws;            // 2,097,152 f32 (reused as y1)
  float* res     = y2 + 2097152;            // 2,097,152 f32
  bf16*  qf      = (bf16*)(res + 2097152);  // 3 x 2,097,152 bf16
  bf16*  kf      = qf + 2097152;
  bf16*  vf      = kf + 2097152;
  float* partial = (float*)(vf + 2097152);  // 512*128 f32
  float* stats2  = partial + 65536;
  float* stats1  = stats2 + 256;

  size_t NEED = (size_t)((char*)(stats1 + 256) - (char*)d_ws);
  if (ws_size < NEED) {
    k_code<<<1, 64, 0, stream>>>((float*)d_out, 2097152.f);
    return;
  }

  k_lin     <<<512, 256, 0, stream>>>(np_, c2_w, c2_b, y2, partial);
  k_finalize<<<8, 256, 0, stream>>>(partial, bn2_g, bn2_b, stats2);
  k_qkv     <<<1536, 256, 0, stream>>>(y2, stats2, wq, wk, wv, qf, kf, vf);
  k_attn    <<<256, 512, 0, stream>>>(qf, kf, vf, knn, pose,
                                      d_w1, d_b1, d_w2, d_b2,
                                      g_w1, g_b1, g_w2, g_b2, res);
  k_lin     <<<512, 256, 0, stream>>>(res, c1_w, c1_b, y2, partial);
  k_finalize<<<8, 256, 0, stream>>>(partial, bn1_g, bn1_b, stats1);
  k_out     <<<2048, 256, 0, stream>>>(y2, stats1, np_, (float*)d_out);
}

// Round 20
// 203.291 us; speedup vs baseline: 1.1071x; 1.1071x over previous
//
#include <hip/hip_runtime.h>
#include <hip/hip_bf16.h>

typedef __bf16 bf16;
typedef __bf16 bf16x4 __attribute__((ext_vector_type(4)));
typedef __bf16 bf16x8 __attribute__((ext_vector_type(8)));
typedef float  f32x4  __attribute__((ext_vector_type(4)));

#define NN 4096
#define KK 16
#define CC 128
#define BN_TOT 16384

// ---------------------------------------------------------------------------
// K1/K5: Y = A(f32) @ W^T(f32) + b (fp32 out) + bn partials.  MFMA 16x16x32.
// SPLIT by output-column half: 512 blocks (row-group x col-half), 256 thr.
// 34 KB LDS -> 2 blocks/CU; each block stages 32 KB of W.
// partial[blk*128 + 0..63]=sum, [64..127]=sumsq for channels ch*64+j.
// ---------------------------------------------------------------------------
__global__ __launch_bounds__(256) void k_lin(
    const float* __restrict__ A, const float* __restrict__ W,
    const float* __restrict__ bias, float* __restrict__ Y,
    float* __restrict__ partial) {
  __shared__ __attribute__((aligned(16))) bf16 WF[16 * 64 * 8];   // 16384 B
  __shared__ __attribute__((aligned(16))) float SF[4][16][68];    // 17408 B
  __shared__ float P1[64], P2[64];
  int tid = threadIdx.x, w = tid >> 6, l = tid & 63, quad = l >> 4, col = l & 15;
  int rb = blockIdx.x >> 1, ch = blockIdx.x & 1;
  int r0 = rb * 64, cbase = ch * 64;
  int arow = r0 + w * 16 + col;

  if (tid < 64) { P1[tid] = 0.f; P2[tid] = 0.f; }

  // stage W rows cbase..cbase+63 (64x128 f32 -> bf16), fragment-linear
  for (int e = tid; e < 64 * 16; e += 256) {
    int r = e >> 4, c8 = e & 15;
    const float* p = W + (cbase + r) * CC + c8 * 8;
    f32x4 v0 = *(const f32x4*)p, v1 = *(const f32x4*)(p + 4);
    bf16x8 o;
    for (int i = 0; i < 4; i++) { o[i] = (bf16)v0[i]; o[i + 4] = (bf16)v1[i]; }
    int chunk = (r >> 4) * 4 + (c8 >> 2);
    int lane  = (c8 & 3) * 16 + (r & 15);
    *(bf16x8*)(&WF[(chunk * 64 + lane) * 8]) = o;
  }

  // A-frags direct from global (full K=128)
  bf16x8 a[4];
  for (int kc = 0; kc < 4; kc++) {
    int c0 = kc * 32 + quad * 8;
    f32x4 y0 = *(const f32x4*)(A + arow * CC + c0);
    f32x4 y1 = *(const f32x4*)(A + arow * CC + c0 + 4);
    bf16x8 o;
    for (int i = 0; i < 4; i++) { o[i] = (bf16)y0[i]; o[i + 4] = (bf16)y1[i]; }
    a[kc] = o;
  }

  f32x4 D[4];
  for (int jb = 0; jb < 4; jb++) {
    float bv = bias[cbase + jb * 16 + col];
    D[jb] = (f32x4){bv, bv, bv, bv};
  }
  __syncthreads();
  for (int jb = 0; jb < 4; jb++)
    for (int kc = 0; kc < 4; kc++) {
      bf16x8 bfrag = *(const bf16x8*)(&WF[((jb * 4 + kc) * 64 + l) * 8]);
      D[jb] = __builtin_amdgcn_mfma_f32_16x16x32_bf16(a[kc], bfrag, D[jb], 0, 0, 0);
    }

  // bn partials (this block's 64 rows x 64 channels)
  for (int jb = 0; jb < 4; jb++) {
    float t1 = D[jb][0] + D[jb][1] + D[jb][2] + D[jb][3];
    float t2 = D[jb][0] * D[jb][0] + D[jb][1] * D[jb][1]
             + D[jb][2] * D[jb][2] + D[jb][3] * D[jb][3];
    t1 += __shfl_xor(t1, 16); t1 += __shfl_xor(t1, 32);
    t2 += __shfl_xor(t2, 16); t2 += __shfl_xor(t2, 32);
    if (quad == 0) {
      atomicAdd(&P1[jb * 16 + col], t1);
      atomicAdd(&P2[jb * 16 + col], t2);
    }
  }

  // fp32 store via per-wave f32 scratch (wave-local: no barrier needed)
  for (int jb = 0; jb < 4; jb++)
    for (int g = 0; g < 4; g++)
      SF[w][quad * 4 + g][jb * 16 + col] = D[jb][g];
  int orow = r0 + w * 16 + (l >> 2), oc = (l & 3) * 16;
  for (int c4 = 0; c4 < 4; c4++) {
    f32x4 v = *(const f32x4*)(&SF[w][l >> 2][oc + c4 * 4]);
    *(f32x4*)(Y + orow * CC + cbase + oc + c4 * 4) = v;
  }

  __syncthreads();  // all waves' LDS atomics done
  if (tid < 64) {
    partial[blockIdx.x * 128 + tid] = P1[tid];
    partial[blockIdx.x * 128 + 64 + tid] = P2[tid];
  }
}

// ---------------------------------------------------------------------------
// PARALLEL finalize: 8 blocks x 256 thr.  Block b owns channels b*16..b*16+15;
// thread (t&15)=channel offset, (t>>4)=group g sums rb = g, g+16, ..., g+240.
// ---------------------------------------------------------------------------
__global__ __launch_bounds__(256) void k_finalize(
    const float* __restrict__ partial, const float* __restrict__ g,
    const float* __restrict__ b, float* __restrict__ stats) {
  __shared__ float sh[2][16][16];
  int t = threadIdx.x, cl = t & 15, gr = t >> 4;   // 16 groups of 16 channels
  int c = blockIdx.x * 16 + cl;
  int ch = c >> 6, j = c & 63;
  float s1 = 0.f, s2 = 0.f;
  for (int rb = gr; rb < 256; rb += 16) {
    const float* pp = partial + (rb * 2 + ch) * 128;
    s1 += pp[j];
    s2 += pp[64 + j];
  }
  sh[0][gr][cl] = s1; sh[1][gr][cl] = s2;
  __syncthreads();
  if (t < 16) {
    s1 = 0.f; s2 = 0.f;
    for (int hh = 0; hh < 16; hh++) {
      s1 += sh[0][hh][t];
      s2 += sh[1][hh][t];
    }
    int cc = blockIdx.x * 16 + t;
    float mean = s1 * (1.0f / BN_TOT);
    float var  = s2 * (1.0f / BN_TOT) - mean * mean;
    float r = rsqrtf(var + 1e-5f);
    float sc = g[cc] * r;
    stats[cc] = sc;
    stats[128 + cc] = b[cc] - mean * sc;
  }
}

// ---------------------------------------------------------------------------
// K3: x = relu(bn2(y2)); q/k/v = x @ W^T (bf16 out).  768 blocks; XCD-swizzled
// so the 3 m-blocks of each row-slice share an XCD L2 (y2 read once per XCD).
// ---------------------------------------------------------------------------
__global__ __launch_bounds__(256) void k_qkv(
    const float* __restrict__ Y, const float* __restrict__ stats,
    const float* __restrict__ Wq, const float* __restrict__ Wk, const float* __restrict__ Wv,
    bf16* __restrict__ Qo, bf16* __restrict__ Ko, bf16* __restrict__ Vo) {
  __shared__ __attribute__((aligned(16))) bf16 WF[32 * 64 * 8];   // 32768 B
  __shared__ __attribute__((aligned(16))) bf16 S[4][16][132];     // 16896 B
  int tid = threadIdx.x, w = tid >> 6, l = tid & 63, quad = l >> 4, col = l & 15;
  int j8 = blockIdx.x >> 3, x8 = blockIdx.x & 7;
  int m = j8 >> 5;                    // weight matrix
  int rb = x8 * 32 + (j8 & 31);       // row-slice; XCD x8 gets rb in [x8*32, x8*32+32)
  int r0 = rb * 64;
  int arow = r0 + w * 16 + col;
  const float* Wg = (m == 0) ? Wq : (m == 1) ? Wk : Wv;
  bf16* Os = (m == 0) ? Qo : (m == 1) ? Ko : Vo;

  for (int e = tid; e < 128 * 16; e += 256) {
    int r = e >> 4, c8 = e & 15;
    const float* p = Wg + r * CC + c8 * 8;
    f32x4 v0 = *(const f32x4*)p, v1 = *(const f32x4*)(p + 4);
    bf16x8 o;
    for (int i = 0; i < 4; i++) { o[i] = (bf16)v0[i]; o[i + 4] = (bf16)v1[i]; }
    int chunk = (r >> 4) * 4 + (c8 >> 2);
    int lane  = (c8 & 3) * 16 + (r & 15);
    *(bf16x8*)(&WF[(chunk * 64 + lane) * 8]) = o;
  }

  // A-frags: x = relu(bn(Y)) -> bf16, in fragment layout
  bf16x8 a[4];
  for (int kc = 0; kc < 4; kc++) {
    int c0 = kc * 32 + quad * 8;
    f32x4 y0  = *(const f32x4*)(Y + arow * CC + c0);
    f32x4 y1  = *(const f32x4*)(Y + arow * CC + c0 + 4);
    f32x4 sc0 = *(const f32x4*)(stats + c0);
    f32x4 sc1 = *(const f32x4*)(stats + c0 + 4);
    f32x4 sf0 = *(const f32x4*)(stats + 128 + c0);
    f32x4 sf1 = *(const f32x4*)(stats + 128 + c0 + 4);
    bf16x8 o;
    for (int i = 0; i < 4; i++) {
      o[i]     = (bf16)fmaxf(y0[i] * sc0[i] + sf0[i], 0.f);
      o[i + 4] = (bf16)fmaxf(y1[i] * sc1[i] + sf1[i], 0.f);
    }
    a[kc] = o;
  }

  __syncthreads();
  f32x4 D[8];
  for (int jb = 0; jb < 8; jb++) D[jb] = (f32x4){0.f, 0.f, 0.f, 0.f};
  for (int jb = 0; jb < 8; jb++)
    for (int kc = 0; kc < 4; kc++) {
      bf16x8 bfrag = *(const bf16x8*)(&WF[((jb * 4 + kc) * 64 + l) * 8]);
      D[jb] = __builtin_amdgcn_mfma_f32_16x16x32_bf16(a[kc], bfrag, D[jb], 0, 0, 0);
    }
  for (int jb = 0; jb < 8; jb++)
    for (int g = 0; g < 4; g++)
      S[w][quad * 4 + g][jb * 16 + col] = (bf16)D[jb][g];
  int orow = r0 + w * 16 + (l >> 2), oc0 = (l & 3) * 32;
  for (int c8 = 0; c8 < 4; c8++) {
    bf16x8 v = *(const bf16x8*)(&S[w][l >> 2][oc0 + c8 * 8]);
    *(bf16x8*)(Os + orow * CC + oc0 + c8 * 8) = v;
  }
}

// ---------------------------------------------------------------------------
// K4: MFMA attention core — best measured (r13/r14/r16/r18: ~68us, VGPR 112).
// 512 thr = 8 waves; 64 points/block (8/wave); grid 256 (XCD-chunked).
// All weights LDS-resident; h1 via padded MFMA; no-max softmax; V-gather +
// K-row loads hoisted under MFMA phases; knn/pose double-buffered.
// A-frag: lane holds X[m=l&15][k=quad*8+j].  D: row=quad*4+g, col=jb*16+(l&15).
// ---------------------------------------------------------------------------
__global__ __launch_bounds__(512) void k_attn(
    const bf16* __restrict__ Q, const bf16* __restrict__ Kf, const bf16* __restrict__ Vf,
    const int* __restrict__ knn, const float* __restrict__ pose,
    const float* __restrict__ d_w1, const float* __restrict__ d_b1,
    const float* __restrict__ d_w2, const float* __restrict__ d_b2,
    const float* __restrict__ g_w1, const float* __restrict__ g_b1,
    const float* __restrict__ g_w2, const float* __restrict__ g_b2,
    float* __restrict__ Rs) {
  __shared__ __attribute__((aligned(16))) bf16 WF[104 * 64 * 8];  // 106496 B
  __shared__ __attribute__((aligned(16))) bf16 S[8][16][132];     // 33792 B
  __shared__ float BSf[512];                                      // 2048 B

  int tid = threadIdx.x, w = tid >> 6, l = tid & 63, quad = l >> 4, col = l & 15;
  int bid = (blockIdx.x & 7) * 32 + (blockIdx.x >> 3);  // XCD-chunked swizzle

  // stage the three 128x128 weights, fragment-linear (chunks 0..95)
  const float* Wg3[3] = {d_w2, g_w1, g_w2};
  for (int m = 0; m < 3; m++) {
    const float* Wg = Wg3[m];
    for (int e = tid; e < 128 * 16; e += 512) {
      int r = e >> 4, c8 = e & 15;
      const float* p = Wg + r * CC + c8 * 8;
      f32x4 v0 = *(const f32x4*)p, v1 = *(const f32x4*)(p + 4);
      bf16x8 o;
      for (int i = 0; i < 4; i++) { o[i] = (bf16)v0[i]; o[i + 4] = (bf16)v1[i]; }
      int chunk = m * 32 + (r >> 4) * 4 + (c8 >> 2);
      int lane  = (c8 & 3) * 16 + (r & 15);
      *(bf16x8*)(&WF[(chunk * 64 + lane) * 8]) = o;
    }
  }
  // d_w1 as K=4-in-32 padded B-frags (chunks 96..103): nonzero only quad 0, j<4
  for (int e = tid; e < 8 * 64; e += 512) {
    int jb = e >> 6, lane = e & 63, q = lane >> 4, c = lane & 15;
    bf16x8 o;
    for (int i = 0; i < 8; i++) o[i] = (bf16)0.f;
    if (q == 0) {
      f32x4 v = *(const f32x4*)(d_w1 + (jb * 16 + c) * 4);
      for (int i = 0; i < 4; i++) o[i] = (bf16)v[i];
    }
    *(bf16x8*)(&WF[((96 + jb) * 64 + lane) * 8]) = o;
  }
  // biases: d_b1 | d_b2 | g_b1 | g_b2
  if (tid < 512) {
    const float* bp = (tid < 128) ? d_b1 : (tid < 256) ? d_b2
                     : (tid < 384) ? g_b1 : g_b2;
    BSf[tid] = bp[tid & 127];
  }
  __syncthreads();

  const float smc = 0.08838834764831845f;  // 1/sqrt(128)

  // preload point 0's knn/pose
  int gpf = bid * 64 + w * 8;
  int i16 = knn[gpf * KK + col];
  f32x4 ps = *(const f32x4*)(pose + gpf * 64 + col * 4);

#pragma unroll 1
  for (int p = 0; p < 8; p++) {
    int gp = bid * 64 + w * 8 + p;
    int b  = gp >> 12;

    // --- EARLY V gather (consumed at vpos; covered by h1+pos MFMAs) ---
    int vidx[4];
#pragma unroll
    for (int g = 0; g < 4; g++) vidx[g] = __shfl(i16, quad * 4 + g);
    float vv[8][4];
#pragma unroll
    for (int g = 0; g < 4; g++) {
      const bf16* vr = Vf + ((b << 12) + vidx[g]) * CC + col;
#pragma unroll
      for (int jb = 0; jb < 8; jb++) vv[jb][g] = (float)vr[jb * 16];
    }
    int grow = (b << 12) + i16;

    // --- h1 = relu(pose @ d_w1^T + d_b1) via padded MFMA (K=4 in 32) ---
    bf16x8 ap;
#pragma unroll
    for (int j = 0; j < 8; j++) ap[j] = (bf16)0.f;
    if (quad == 0) {
#pragma unroll
      for (int j = 0; j < 4; j++) ap[j] = (bf16)ps[j];
    }
    f32x4 D[8];
#pragma unroll
    for (int jb = 0; jb < 8; jb++) {
      float bv = BSf[jb * 16 + col];
      D[jb] = (f32x4){bv, bv, bv, bv};
      bf16x8 bfrag = *(const bf16x8*)(&WF[((96 + jb) * 64 + l) * 8]);
      D[jb] = __builtin_amdgcn_mfma_f32_16x16x32_bf16(ap, bfrag, D[jb], 0, 0, 0);
    }
#pragma unroll
    for (int jb = 0; jb < 8; jb++)
#pragma unroll
      for (int g = 0; g < 4; g++)
        S[w][quad * 4 + g][jb * 16 + col] = (bf16)fmaxf(D[jb][g], 0.f);
    bf16x8 aA[4];
#pragma unroll
    for (int kc = 0; kc < 4; kc++)
      aA[kc] = *(const bf16x8*)(&S[w][col][kc * 32 + quad * 8]);

    // --- EARLY K-row loads (consumed in h-phase; covered by pos MFMAs) ---
    bf16x8 kkv[4];
#pragma unroll
    for (int kc = 0; kc < 4; kc++)
      kkv[kc] = *(const bf16x8*)(Kf + grow * CC + kc * 32 + quad * 8);

    // --- prefetch next point's knn/pose ---
    if (p < 7) {
      i16 = knn[(gp + 1) * KK + col];
      ps  = *(const f32x4*)(pose + (gp + 1) * 64 + col * 4);
    }

    // --- pos = h1 @ d_w2^T + d_b2  (B-frags from LDS chunks 0..31) ---
#pragma unroll
    for (int jb = 0; jb < 8; jb++) {
      float bv = BSf[128 + jb * 16 + col];
      D[jb] = (f32x4){bv, bv, bv, bv};
    }
#pragma unroll
    for (int jb = 0; jb < 8; jb++)
#pragma unroll
      for (int kc = 0; kc < 4; kc++) {
        bf16x8 bfrag = *(const bf16x8*)(&WF[((jb * 4 + kc) * 64 + l) * 8]);
        D[jb] = __builtin_amdgcn_mfma_f32_16x16x32_bf16(aA[kc], bfrag, D[jb], 0, 0, 0);
      }

    // --- vpos = vv + pos (in place) ---
#pragma unroll
    for (int jb = 0; jb < 8; jb++)
#pragma unroll
      for (int g = 0; g < 4; g++) vv[jb][g] += D[jb][g];

    // --- pos -> S; h = q - kk + pos in A layout ---
#pragma unroll
    for (int jb = 0; jb < 8; jb++)
#pragma unroll
      for (int g = 0; g < 4; g++)
        S[w][quad * 4 + g][jb * 16 + col] = (bf16)D[jb][g];
#pragma unroll
    for (int kc = 0; kc < 4; kc++) {
      int c0 = kc * 32 + quad * 8;
      bf16x8 qv = *(const bf16x8*)(Q + gp * CC + c0);
      bf16x8 pv = *(const bf16x8*)(&S[w][col][c0]);
      bf16x8 hv;
#pragma unroll
      for (int j = 0; j < 8; j++)
        hv[j] = (bf16)((float)qv[j] - (float)kkv[kc][j] + (float)pv[j]);
      aA[kc] = hv;
    }

    // --- t = relu(h @ g_w1^T + g_b1)  (chunks 32..63) ---
#pragma unroll
    for (int jb = 0; jb < 8; jb++) {
      float bv = BSf[256 + jb * 16 + col];
      D[jb] = (f32x4){bv, bv, bv, bv};
    }
#pragma unroll
    for (int jb = 0; jb < 8; jb++)
#pragma unroll
      for (int kc = 0; kc < 4; kc++) {
        bf16x8 bfrag = *(const bf16x8*)(&WF[((32 + jb * 4 + kc) * 64 + l) * 8]);
        D[jb] = __builtin_amdgcn_mfma_f32_16x16x32_bf16(aA[kc], bfrag, D[jb], 0, 0, 0);
      }
#pragma unroll
    for (int jb = 0; jb < 8; jb++)
#pragma unroll
      for (int g = 0; g < 4; g++)
        S[w][quad * 4 + g][jb * 16 + col] = (bf16)fmaxf(D[jb][g], 0.f);
#pragma unroll
    for (int kc = 0; kc < 4; kc++)
      aA[kc] = *(const bf16x8*)(&S[w][col][kc * 32 + quad * 8]);

    // --- logits = t @ g_w2^T + g_b2  (chunks 64..95) ---
#pragma unroll
    for (int jb = 0; jb < 8; jb++) {
      float bv = BSf[384 + jb * 16 + col];
      D[jb] = (f32x4){bv, bv, bv, bv};
    }
#pragma unroll
    for (int jb = 0; jb < 8; jb++)
#pragma unroll
      for (int kc = 0; kc < 4; kc++) {
        bf16x8 bfrag = *(const bf16x8*)(&WF[((64 + jb * 4 + kc) * 64 + l) * 8]);
        D[jb] = __builtin_amdgcn_mfma_f32_16x16x32_bf16(aA[kc], bfrag, D[jb], 0, 0, 0);
      }

    // --- softmax over k (no max-sub: logits bounded ~O(1); proven r5-r18) ---
#pragma unroll
    for (int jb = 0; jb < 8; jb++) {
      float s = 0.f, pa = 0.f;
#pragma unroll
      for (int g = 0; g < 4; g++) {
        float e = __expf(D[jb][g] * smc);
        s += e; pa += e * vv[jb][g];
      }
      s  += __shfl_xor(s, 16);  s += __shfl_xor(s, 32);
      pa += __shfl_xor(pa, 16); pa += __shfl_xor(pa, 32);
      if (quad == 0) Rs[gp * CC + jb * 16 + col] = pa / s;
    }
  }
}

// ---------------------------------------------------------------------------
// K7: out = relu(bn1(y1)) + new_points   (fp32 out)
// ---------------------------------------------------------------------------
__global__ __launch_bounds__(256) void k_out(
    const float* __restrict__ Y, const float* __restrict__ stats,
    const float* __restrict__ NP, float* __restrict__ Out) {
  int i0 = (blockIdx.x * 256 + threadIdx.x) * 4;
  int c0 = i0 & 127;
  f32x4 y  = *(const f32x4*)(Y + i0);
  f32x4 sc = *(const f32x4*)(stats + c0);
  f32x4 sh = *(const f32x4*)(stats + 128 + c0);
  f32x4 np = *(const f32x4*)(NP + i0);
  f32x4 o;
  for (int i = 0; i < 4; i++)
    o[i] = fmaxf(y[i] * sc[i] + sh[i], 0.f) + np[i];
  *(f32x4*)(Out + i0) = o;
}

__global__ void k_code(float* out, float code) {
  if (threadIdx.x == 0) out[1000003] = code;
}

// ---------------------------------------------------------------------------
extern "C" void kernel_launch(void* const* d_in, const int* in_sizes, int n_in,
                              void* d_out, int out_size, void* d_ws, size_t ws_size,
                              hipStream_t stream) {
  static const int expect[22] = {
    1048576, 262144, 2097152, 16384, 16384, 16384,
    16384, 128, 16384, 128,
    512, 128, 16384, 128,
    16384, 128, 128, 128,
    16384, 128, 128, 128
  };
  if (n_in != 22) { k_code<<<1, 64, 0, stream>>>((float*)d_out, 4194304.f); return; }
  for (int i = 0; i < 22; i++)
    if (in_sizes[i] != expect[i]) {
      k_code<<<1, 64, 0, stream>>>((float*)d_out, 262144.f * (float)(i + 1));
      return;
    }

  const float* pose  = (const float*)d_in[0];
  const int*   knn   = (const int*)d_in[1];
  const float* np_   = (const float*)d_in[2];
  const float* wq    = (const float*)d_in[3];
  const float* wk    = (const float*)d_in[4];
  const float* wv    = (const float*)d_in[5];
  const float* g_w1  = (const float*)d_in[6];
  const float* g_b1  = (const float*)d_in[7];
  const float* g_w2  = (const float*)d_in[8];
  const float* g_b2  = (const float*)d_in[9];
  const float* d_w1  = (const float*)d_in[10];
  const float* d_b1  = (const float*)d_in[11];
  const float* d_w2  = (const float*)d_in[12];
  const float* d_b2  = (const float*)d_in[13];
  const float* c1_w  = (const float*)d_in[14];
  const float* c1_b  = (const float*)d_in[15];
  const float* bn1_g = (const float*)d_in[16];
  const float* bn1_b = (const float*)d_in[17];
  const float* c2_w  = (const float*)d_in[18];
  const float* c2_b  = (const float*)d_in[19];
  const float* bn2_g = (const float*)d_in[20];
  const float* bn2_b = (const float*)d_in[21];

  float* y2      = (float*)d_ws;            // 2,097,152 f32 (reused as y1)
  float* res     = y2 + 2097152;            // 2,097,152 f32
  bf16*  qf      = (bf16*)(res + 2097152);  // 3 x 2,097,152 bf16
  bf16*  kf      = qf + 2097152;
  bf16*  vf      = kf + 2097152;
  float* partial = (float*)(vf + 2097152);  // 512*128 f32
  float* stats2  = partial + 65536;
  float* stats1  = stats2 + 256;

  size_t NEED = (size_t)((char*)(stats1 + 256) - (char*)d_ws);
  if (ws_size < NEED) {
    k_code<<<1, 64, 0, stream>>>((float*)d_out, 2097152.f);
    return;
  }

  k_lin     <<<512, 256, 0, stream>>>(np_, c2_w, c2_b, y2, partial);
  k_finalize<<<8, 256, 0, stream>>>(partial, bn2_g, bn2_b, stats2);
  k_qkv     <<<768, 256, 0, stream>>>(y2, stats2, wq, wk, wv, qf, kf, vf);
  k_attn    <<<256, 512, 0, stream>>>(qf, kf, vf, knn, pose,
                                      d_w1, d_b1, d_w2, d_b2,
                                      g_w1, g_b1, g_w2, g_b2, res);
  k_lin     <<<512, 256, 0, stream>>>(res, c1_w, c1_b, y2, partial);
  k_finalize<<<8, 256, 0, stream>>>(partial, bn1_g, bn1_b, stats1);
  k_out     <<<2048, 256, 0, stream>>>(y2, stats1, np_, (float*)d_out);
}